// Round 1
// 960.727 us; speedup vs baseline: 1.1555x; 1.1555x over previous
//
#include <hip/hip_runtime.h>
#include <hip/hip_bf16.h>
#include <stdint.h>

#define N_TOKENS 16384
#define D_IN 1024
#define D_OUT 1024
#define N_EXPS 8

typedef __bf16 bf16x8 __attribute__((ext_vector_type(8)));
typedef float f32x4 __attribute__((ext_vector_type(4)));

typedef __attribute__((address_space(1))) void gvoid_t;
typedef __attribute__((address_space(3))) void lvoid_t;

__device__ __forceinline__ void async_copy16(void* lds, const void* g) {
    __builtin_amdgcn_global_load_lds((gvoid_t*)g, (lvoid_t*)lds, 16, 0, 0);
}

__device__ __forceinline__ unsigned short f2bf_u16(float f) {
    union { __hip_bfloat16 h; unsigned short u; } cv;
    cv.h = __float2bfloat16(f);
    return cv.u;
}

// Kernel 1: gating softmax (fp32) + embs -> bf16 conversion. One wave per token.
__global__ __launch_bounds__(256) void gate_convert_kernel(
    const float* __restrict__ embs, const float* __restrict__ expsT,
    unsigned short* __restrict__ embs_bf, float* __restrict__ probs) {
    const int row  = blockIdx.x * 4 + (threadIdx.x >> 6);
    const int lane = threadIdx.x & 63;
    const float* er = embs + (size_t)row * D_IN;

    float s[N_EXPS];
#pragma unroll
    for (int e = 0; e < N_EXPS; ++e) s[e] = 0.f;

#pragma unroll
    for (int j = 0; j < 4; ++j) {
        const int chunk = j * 64 + lane;
        const float4 v = ((const float4*)er)[chunk];
        const int d = chunk * 4;
        const float vv[4] = {v.x, v.y, v.z, v.w};
#pragma unroll
        for (int q = 0; q < 4; ++q) {
            const float4 t0 = ((const float4*)(expsT + (size_t)(d + q) * N_EXPS))[0];
            const float4 t1 = ((const float4*)(expsT + (size_t)(d + q) * N_EXPS))[1];
            s[0] += vv[q] * t0.x; s[1] += vv[q] * t0.y;
            s[2] += vv[q] * t0.z; s[3] += vv[q] * t0.w;
            s[4] += vv[q] * t1.x; s[5] += vv[q] * t1.y;
            s[6] += vv[q] * t1.z; s[7] += vv[q] * t1.w;
        }
        ushort4 u;
        u.x = f2bf_u16(v.x); u.y = f2bf_u16(v.y);
        u.z = f2bf_u16(v.z); u.w = f2bf_u16(v.w);
        ((ushort4*)embs_bf)[(size_t)row * 256 + chunk] = u;
    }

#pragma unroll
    for (int off = 32; off; off >>= 1) {
#pragma unroll
        for (int e = 0; e < N_EXPS; ++e) s[e] += __shfl_xor(s[e], off, 64);
    }

    float mx = s[0];
#pragma unroll
    for (int e = 1; e < N_EXPS; ++e) mx = fmaxf(mx, s[e]);
    float pe[N_EXPS];
    float sum = 0.f;
#pragma unroll
    for (int e = 0; e < N_EXPS; ++e) { pe[e] = __expf(s[e] - mx); sum += pe[e]; }
    const float inv = 1.f / sum;
    if (lane == 0) {
#pragma unroll
        for (int e = 0; e < N_EXPS; ++e) probs[(size_t)row * N_EXPS + e] = pe[e] * inv;
    }
}

// Kernel 2: expert_W -> bf16 conversion + c[e][o] = dot(bias_e, W[e][o]). One wave per (e,o) row.
__global__ __launch_bounds__(256) void wconv_kernel(
    const float* __restrict__ W, const float* __restrict__ bias,
    unsigned short* __restrict__ Wbf, float* __restrict__ cvec) {
    const int gw   = blockIdx.x * 4 + (threadIdx.x >> 6);  // 0..8191 = e*1024+o
    const int lane = threadIdx.x & 63;
    const int e    = gw >> 10;
    const float* wr = W + (size_t)gw * D_IN;
    const float* br = bias + (size_t)e * D_IN;

    float dot = 0.f;
#pragma unroll
    for (int j = 0; j < 4; ++j) {
        const int chunk = j * 64 + lane;
        const float4 w4 = ((const float4*)wr)[chunk];
        const float4 b4 = ((const float4*)br)[chunk];
        dot += w4.x * b4.x + w4.y * b4.y + w4.z * b4.z + w4.w * b4.w;
        ushort4 u;
        u.x = f2bf_u16(w4.x); u.y = f2bf_u16(w4.y);
        u.z = f2bf_u16(w4.z); u.w = f2bf_u16(w4.w);
        ((ushort4*)Wbf)[(size_t)gw * 256 + chunk] = u;
    }
#pragma unroll
    for (int off = 32; off; off >>= 1) dot += __shfl_xor(dot, off, 64);
    if (lane == 0) cvec[gw] = dot;
}

// Kernel 3: fused 8-expert bf16 GEMM, EXPERT-PAIRED (A staged once per pair),
// non-temporal output stores (protect LLC residency of A/B).
// Block = 256 thr (4 waves, 2x2), tile 128x128, BK=32, MFMA 16x16x32 bf16, 4x4 per wave per expert.
__global__ __launch_bounds__(256, 2) void moe_gemm_kernel(
    const __hip_bfloat16* __restrict__ Abf, const __hip_bfloat16* __restrict__ Wbf,
    const float* __restrict__ probs, const float* __restrict__ cvec,
    float* __restrict__ out_multi, float* __restrict__ out_exp) {
    constexpr int BM = 128, BN = 128, BK = 32;
    __shared__ __align__(16) __hip_bfloat16 As[BM * BK];
    __shared__ __align__(16) __hip_bfloat16 Bs[2][BN * BK];
    __shared__ float p_lds[N_EXPS][BM];
    __shared__ float c_lds[N_EXPS][BN];

    const int tid  = threadIdx.x;
    const int lane = tid & 63;
    const int lm   = lane & 15;
    const int lq   = lane >> 4;
    const int wave = tid >> 6;
    const int wm   = (wave >> 1) * 64;
    const int wn   = (wave & 1) * 64;
    const int nT   = blockIdx.x & 7;   // nT == XCD (round-robin) -> B column stays in one L2
    const int mT   = blockIdx.x >> 3;
    const int m0   = mT * BM;
    const int n0   = nT * BN;

    // Stage per-row probs and per-col c into LDS (used only in epilogues, after barriers).
    for (int i = tid; i < N_EXPS * BM; i += 256)
        p_lds[i >> 7][i & 127] = probs[(size_t)(m0 + (i & 127)) * N_EXPS + (i >> 7)];
    for (int i = tid; i < N_EXPS * BN; i += 256)
        c_lds[i >> 7][i & 127] = cvec[(size_t)(i >> 7) * D_OUT + n0 + (i & 127)];

    // global_load_lds staging: 512 chunks of 16B per tile, 2 issues/thread.
    // chunk c = issue*256 + tid; row = c>>2, kchunk = c&3; LDS slot = c*16B (linear).
    const int c0 = tid, c1 = 256 + tid;
    const __hip_bfloat16* gA0 = Abf + (size_t)(m0 + (c0 >> 2)) * D_IN + (c0 & 3) * 8;
    const __hip_bfloat16* gA1 = Abf + (size_t)(m0 + (c1 >> 2)) * D_IN + (c1 & 3) * 8;
    const __hip_bfloat16* gB0 = Wbf + (size_t)(n0 + (c0 >> 2)) * D_IN + (c0 & 3) * 8;
    const __hip_bfloat16* gB1 = Wbf + (size_t)(n0 + (c1 >> 2)) * D_IN + (c1 & 3) * 8;
    __hip_bfloat16* lA0  = As + (tid & ~63) * 8;   // wave-uniform LDS base
    __hip_bfloat16* lA1  = lA0 + 2048;
    __hip_bfloat16* lB00 = Bs[0] + (tid & ~63) * 8;
    __hip_bfloat16* lB01 = lB00 + 2048;
    __hip_bfloat16* lB10 = Bs[1] + (tid & ~63) * 8;
    __hip_bfloat16* lB11 = lB10 + 2048;

    // Fragment bases: per-t offsets are +t*16*BK elements (folds into ds_read imm offset).
    const int abase = (wm + lm) * BK + lq * 8;
    const int bbase = (wn + lm) * BK + lq * 8;

    float multi[4][4][4];
#pragma unroll
    for (int ti = 0; ti < 4; ++ti)
#pragma unroll
        for (int tj = 0; tj < 4; ++tj)
#pragma unroll
            for (int r = 0; r < 4; ++r) multi[ti][tj][r] = 0.f;

    const f32x4 fzero = {0.f, 0.f, 0.f, 0.f};

    // Epilogue: val = dot - c_e[o]; write expert_outputs (non-temporal); multi += p * val.
    auto epilogue = [&](int e, f32x4 (&acc)[4][4]) {
        float cv[4];
#pragma unroll
        for (int tj = 0; tj < 4; ++tj) cv[tj] = c_lds[e][wn + tj * 16 + lm];
#pragma unroll
        for (int ti = 0; ti < 4; ++ti) {
#pragma unroll
            for (int r = 0; r < 4; ++r) {
                const int rloc = wm + ti * 16 + lq * 4 + r;
                const int grow = m0 + rloc;
                const float p = p_lds[e][rloc];
                float* orow = out_exp + ((size_t)grow * N_EXPS + e) * D_OUT + n0 + wn;
#pragma unroll
                for (int tj = 0; tj < 4; ++tj) {
                    const float val = acc[ti][tj][r] - cv[tj];
                    __builtin_nontemporal_store(val, &orow[tj * 16 + lm]);
                    multi[ti][tj][r] = fmaf(p, val, multi[ti][tj][r]);
                }
            }
        }
    };

    for (int ep = 0; ep < N_EXPS / 2; ++ep) {
        const int e0 = 2 * ep, e1 = 2 * ep + 1;
        const size_t e0off = (size_t)e0 * D_OUT * D_IN;
        const size_t e1off = (size_t)e1 * D_OUT * D_IN;
        f32x4 acc0[4][4], acc1[4][4];
#pragma unroll
        for (int ti = 0; ti < 4; ++ti)
#pragma unroll
            for (int tj = 0; tj < 4; ++tj) { acc0[ti][tj] = fzero; acc1[ti][tj] = fzero; }

        for (int kt = 0; kt < D_IN / BK; ++kt) {
            const int ko = kt * BK;
            async_copy16(lA0,  gA0 + ko);
            async_copy16(lA1,  gA1 + ko);
            async_copy16(lB00, gB0 + e0off + ko);
            async_copy16(lB01, gB1 + e0off + ko);
            async_copy16(lB10, gB0 + e1off + ko);
            async_copy16(lB11, gB1 + e1off + ko);
            __syncthreads();

            bf16x8 a[4], b[4];
#pragma unroll
            for (int t = 0; t < 4; ++t) a[t] = *(const bf16x8*)(As + abase + t * 16 * BK);
#pragma unroll
            for (int t = 0; t < 4; ++t) b[t] = *(const bf16x8*)(Bs[0] + bbase + t * 16 * BK);
#pragma unroll
            for (int ti = 0; ti < 4; ++ti)
#pragma unroll
                for (int tj = 0; tj < 4; ++tj)
                    acc0[ti][tj] = __builtin_amdgcn_mfma_f32_16x16x32_bf16(
                        a[ti], b[tj], acc0[ti][tj], 0, 0, 0);
            // Reuse b-frag registers for the second expert (keeps us under the 256-reg band).
#pragma unroll
            for (int t = 0; t < 4; ++t) b[t] = *(const bf16x8*)(Bs[1] + bbase + t * 16 * BK);
#pragma unroll
            for (int ti = 0; ti < 4; ++ti)
#pragma unroll
                for (int tj = 0; tj < 4; ++tj)
                    acc1[ti][tj] = __builtin_amdgcn_mfma_f32_16x16x32_bf16(
                        a[ti], b[tj], acc1[ti][tj], 0, 0, 0);
            __syncthreads();
        }

        epilogue(e0, acc0);
        epilogue(e1, acc1);
    }

#pragma unroll
    for (int ti = 0; ti < 4; ++ti) {
#pragma unroll
        for (int r = 0; r < 4; ++r) {
            const int grow = m0 + wm + ti * 16 + lq * 4 + r;
            float* mrow = out_multi + (size_t)grow * D_OUT + n0 + wn;
#pragma unroll
            for (int tj = 0; tj < 4; ++tj)
                __builtin_nontemporal_store(multi[ti][tj][r], &mrow[tj * 16 + lm]);
        }
    }
}

extern "C" void kernel_launch(void* const* d_in, const int* in_sizes, int n_in,
                              void* d_out, int out_size, void* d_ws, size_t ws_size,
                              hipStream_t stream) {
    const float* embs  = (const float*)d_in[0];   // [16384,1024]
    const float* expsT = (const float*)d_in[1];   // [1024,8]
    const float* bias  = (const float*)d_in[2];   // [8,1024]
    const float* W     = (const float*)d_in[3];   // [8,1024,1024]

    float* out_multi = (float*)d_out;                            // [16384,1024]
    float* out_exp   = (float*)d_out + (size_t)N_TOKENS * D_OUT; // [16384,8,1024]

    // workspace layout (~51 MB)
    char* ws = (char*)d_ws;
    unsigned short* embs_bf = (unsigned short*)ws;                         // 33,554,432 B
    unsigned short* W_bf    = (unsigned short*)(ws + 33554432);            // 16,777,216 B
    float*          probs   = (float*)(ws + 33554432 + 16777216);          //    524,288 B
    float*          cvec    = (float*)(ws + 33554432 + 16777216 + 524288); //     32,768 B

    gate_convert_kernel<<<N_TOKENS / 4, 256, 0, stream>>>(embs, expsT, embs_bf, probs);
    wconv_kernel<<<(N_EXPS * D_OUT) / 4, 256, 0, stream>>>(W, bias, W_bf, cvec);
    moe_gemm_kernel<<<(N_TOKENS / 128) * (D_OUT / 128), 256, 0, stream>>>(
        (const __hip_bfloat16*)embs_bf, (const __hip_bfloat16*)W_bf,
        probs, cvec, out_multi, out_exp);
}